// Round 12
// baseline (12827.132 us; speedup 1.0000x reference)
//
#include <hip/hip_runtime.h>
#include <stdint.h>

// T=1024, B=32, D=H=1024.  M = T*B = 32768.
typedef float  f32x4  __attribute__((ext_vector_type(4)));
typedef short  bf16x8 __attribute__((ext_vector_type(8)));
typedef unsigned int u32x4 __attribute__((ext_vector_type(4)));

// ws: [0,64MiB) delta bf16.  Exchange at 64MiB+4KiB:
//   per set (2): 4 groups x 2 parity x 8KB buffers = 64KB   (buf)
//   flags at 64MiB+4KiB+128KiB: per set 4 groups x 128B = 512B
#define EX_OFF  ((64ull << 20) + 4096ull)
#define FL_OFF  ((64ull << 20) + 4096ull + (128ull << 10))

__device__ __forceinline__ unsigned short f2bf(float f) {
  union { float f; unsigned u; } v; v.f = f;
  unsigned r = v.u + 0x7fffu + ((v.u >> 16) & 1u);   // RNE, inputs are finite
  return (unsigned short)(r >> 16);
}
__device__ __forceinline__ float bf2f(unsigned short s) {
  union { unsigned u; float f; } v; v.u = ((unsigned)s) << 16; return v.f;
}
__device__ __forceinline__ bf16x8 pack8(float4 a, float4 b) {
  bf16x8 v;
  v[0]=(short)f2bf(a.x); v[1]=(short)f2bf(a.y); v[2]=(short)f2bf(a.z); v[3]=(short)f2bf(a.w);
  v[4]=(short)f2bf(b.x); v[5]=(short)f2bf(b.y); v[6]=(short)f2bf(b.z); v[7]=(short)f2bf(b.w);
  return v;
}
__device__ __forceinline__ unsigned long long pack4bf(float a, float b, float c, float d) {
  return (unsigned long long)f2bf(a) | ((unsigned long long)f2bf(b) << 16)
       | ((unsigned long long)f2bf(c) << 32) | ((unsigned long long)f2bf(d) << 48);
}
__device__ __forceinline__ f32x4 mfma16(bf16x8 a, bf16x8 b, f32x4 c) {
  return __builtin_amdgcn_mfma_f32_16x16x32_bf16(a, b, c, 0, 0, 0);
}
// fast tanh: 1 - 2/(exp(2y)+1); v_exp/v_rcp are ~1ulp, saturates correctly.
__device__ __forceinline__ float fast_tanh(float y) {
  return 1.0f - 2.0f * __builtin_amdgcn_rcpf(__expf(2.0f * y) + 1.0f);
}

// ---------------------------------------------------------------------------
// Phase 1 (unchanged, known-good): wx = x@Wx^T + bias -> d_out (fp32);
// delta = sigmoid(x@Wd^T + b_delta) -> ws (bf16).
// ---------------------------------------------------------------------------
__global__ __launch_bounds__(256) void proj_kernel(
    const float* __restrict__ x,  const float* __restrict__ Wx,
    const float* __restrict__ Wd, const float* __restrict__ bias,
    const float* __restrict__ bd, float* __restrict__ wx_out,
    unsigned short* __restrict__ delta_out)
{
  __shared__ __align__(16) unsigned short lA[128 * 40];
  __shared__ __align__(16) unsigned short lB[128 * 40];

  const int tid  = threadIdx.x;
  const int lane = tid & 63;
  const int wv   = tid >> 6;
  const int wm   = (wv >> 1) * 64;
  const int wn   = (wv & 1) * 64;
  const int l15  = lane & 15, lhi = lane >> 4;

  const int  bm    = blockIdx.x;
  const int  bn    = blockIdx.y;
  const bool isd   = bn >= 8;
  const float* W   = isd ? Wd : Wx;
  const int  ncol0 = (bn & 7) * 128;
  const int  row0  = bm * 128;

  const int srow = tid >> 1;
  const int scol = (tid & 1) * 16;

  f32x4 acc[4][4] = {};

  for (int k0 = 0; k0 < 1024; k0 += 32) {
    const float* pa = x + (size_t)(row0 + srow) * 1024 + (k0 + scol);
    const float* pb = W + (size_t)(ncol0 + srow) * 1024 + (k0 + scol);
    float4 a0 = *(const float4*)(pa + 0), a1 = *(const float4*)(pa + 4);
    float4 a2 = *(const float4*)(pa + 8), a3 = *(const float4*)(pa + 12);
    float4 b0 = *(const float4*)(pb + 0), b1 = *(const float4*)(pb + 4);
    float4 b2 = *(const float4*)(pb + 8), b3 = *(const float4*)(pb + 12);

    *(bf16x8*)&lA[srow * 40 + scol]     = pack8(a0, a1);
    *(bf16x8*)&lA[srow * 40 + scol + 8] = pack8(a2, a3);
    *(bf16x8*)&lB[srow * 40 + scol]     = pack8(b0, b1);
    *(bf16x8*)&lB[srow * 40 + scol + 8] = pack8(b2, b3);
    __syncthreads();

    bf16x8 af[4], bfr[4];
    #pragma unroll
    for (int i = 0; i < 4; ++i) {
      af[i]  = *(const bf16x8*)&lA[(wm + i * 16 + l15) * 40 + lhi * 8];
      bfr[i] = *(const bf16x8*)&lB[(wn + i * 16 + l15) * 40 + lhi * 8];
    }
    #pragma unroll
    for (int i = 0; i < 4; ++i)
      #pragma unroll
      for (int j = 0; j < 4; ++j)
        acc[i][j] = mfma16(af[i], bfr[j], acc[i][j]);
    __syncthreads();
  }

  #pragma unroll
  for (int i = 0; i < 4; ++i) {
    const int rbase = row0 + wm + i * 16 + lhi * 4;
    #pragma unroll
    for (int j = 0; j < 4; ++j) {
      const int col = ncol0 + wn + j * 16 + l15;
      #pragma unroll
      for (int r = 0; r < 4; ++r) {
        const size_t idx = (size_t)(rbase + r) * 1024 + col;
        const float v = acc[i][j][r];
        if (!isd) {
          wx_out[idx] = v + bias[col];
        } else {
          const float s = 1.0f / (1.0f + expf(-(v + bd[col])));
          delta_out[idx] = f2bf(s);
        }
      }
    }
  }
}

// ---------------------------------------------------------------------------
// Phase 2: D=4 GROUP-INTERLEAVED recurrence (latency hiding, r4 protocol).
// 16 WGs: set = blockIdx>>3 (batches set*16..+15), chunk = blockIdx&7
// (output cols 128*chunk..+127).  Each set's 16 batches split into 4 groups
// of 4; the 8 WGs of a set process g0..g3 round-robin each step.  A group's
// publish->next-poll round trip (~12k cy at the chip-global coherence point)
// is hidden behind the other 3 groups' compute.
// Protocol per group = EXACTLY r4's proven one (the only one that never
// hung): publish stores -> vmcnt(0) drain -> per-wave absolute-step flag ->
// wave-uniform flag-line poll.  The drain is the NEXT group's stage
// vmcnt(0) (free), after which the pending flag is stored.
// All exchange traffic sc0sc1.  Flags memset in-graph each launch.
// LDS tile layout [kt][bl][32 halves] (8KB, 2 tiles alternating by g&1):
// dense contiguous stage-writes, 2-way (free) fragment reads.
// ---------------------------------------------------------------------------
__global__ __launch_bounds__(256, 1) void rnn_kernel(
    const float* __restrict__ R, const float* __restrict__ h0,
    float* __restrict__ out, const unsigned short* __restrict__ delta,
    char* __restrict__ ws)
{
  __shared__ __align__(16) unsigned short hs[2][4096];   // 2 x 8KB tiles

  const int tid  = threadIdx.x;
  const int lane = tid & 63;
  const int wv   = tid >> 6;
  const int l15  = lane & 15, lhi = lane >> 4;
  const int set   = blockIdx.x >> 3;
  const int chunk = blockIdx.x & 7;
  const int cb    = chunk * 128 + wv * 32;     // this wave's 32 output cols

  char* ex = ws + EX_OFF + (size_t)set * 65536;
  unsigned int* flbase = (unsigned int*)(ws + FL_OFF + (size_t)set * 512);
  const int slot = chunk * 4 + wv;             // per-wave flag slot (0..31)

  // R fragments as A-operand (r4-verified layout):
  // ra[nt][kt] = R[cb+nt*16+l15][kt*32+lhi*8 .. +7]
  bf16x8 ra[2][32];
  #pragma unroll
  for (int nt = 0; nt < 2; ++nt) {
    const float* rrow = R + (size_t)(cb + nt * 16 + l15) * 1024 + lhi * 8;
    #pragma unroll
    for (int kt = 0; kt < 32; ++kt) {
      float4 u0 = *(const float4*)(rrow + kt * 32);
      float4 u1 = *(const float4*)(rrow + kt * 32 + 4);
      ra[nt][kt] = pack8(u0, u1);
    }
  }

  const int bl    = l15 & 3;                   // batch-local within group
  const bool valid = (l15 < 4);                // lanes 4..15 duplicate
  const int j00 = cb + lhi * 4, j01 = cb + 16 + lhi * 4;

  // h state for all 4 groups (static indexing via unrolled loops)
  float hloc[4][2][4];
  #pragma unroll
  for (int g = 0; g < 4; ++g) {
    const int b = set * 16 + g * 4 + bl;
    const f32x4 h00 = *(const f32x4*)(h0 + (size_t)b * 1024 + j00);
    const f32x4 h01 = *(const f32x4*)(h0 + (size_t)b * 1024 + j01);
    #pragma unroll
    for (int r = 0; r < 4; ++r) { hloc[g][0][r] = h00[r]; hloc[g][1][r] = h01[r]; }
  }

  // init publish: h0 into each group's parity-0; drain; barrier; flags = 1
  #pragma unroll
  for (int g = 0; g < 4; ++g) {
    if (valid) {
      unsigned short* bp = (unsigned short*)(ex + g * 16384);
      asm volatile("global_store_dwordx2 %0, %1, off sc0 sc1"
        :: "v"(bp + (size_t)bl * 1024 + j00),
           "v"(pack4bf(hloc[g][0][0], hloc[g][0][1], hloc[g][0][2], hloc[g][0][3])) : "memory");
      asm volatile("global_store_dwordx2 %0, %1, off sc0 sc1"
        :: "v"(bp + (size_t)bl * 1024 + j01),
           "v"(pack4bf(hloc[g][1][0], hloc[g][1][1], hloc[g][1][2], hloc[g][1][3])) : "memory");
    }
  }
  asm volatile("s_waitcnt vmcnt(0)" ::: "memory");
  __syncthreads();
  if (lane == 0) {
    #pragma unroll
    for (int g = 0; g < 4; ++g)
      asm volatile("global_store_dword %0, %1, off sc0 sc1"
                   :: "v"(flbase + g * 32 + slot), "v"(1u) : "memory");
  }

  // stage map: thread i loads 32B from buf + ((i>>1)&3)*1024 + (i>>3)*32 +
  // (i&1)*16 halves, writes LDS at byte offset i*32 (dense).
  const int sbl = (tid >> 1) & 3, skt = tid >> 3, sko = (tid & 1) * 16;
  const size_t goff = (size_t)sbl * 1024 + skt * 32 + sko;   // halves

  unsigned pend_val = 0;
  unsigned int* pend_ptr = flbase;             // dummy; gated by pend_val

  for (int t = 0; t < 1024; ++t) {
    const int par = t & 1;
    float*                outp = out + (size_t)t * 32768;
    const unsigned short* dp   = delta + (size_t)t * 32768;
    const unsigned target = (unsigned)t + 1u;

    #pragma unroll
    for (int g = 0; g < 4; ++g) {
      const int b = set * 16 + g * 4 + bl;
      unsigned short* bufin  = (unsigned short*)(ex + g * 16384 + par * 8192);
      unsigned short* bufout = (unsigned short*)(ex + g * 16384 + (par ^ 1) * 8192);
      unsigned int*   flg    = flbase + g * 32;

      // prefetch wx / delta (plain cached; drained by poll's vmcnt)
      f32x4 wx0 = *(const f32x4*)(outp + (size_t)b * 1024 + j00);
      f32x4 wx1 = *(const f32x4*)(outp + (size_t)b * 1024 + j01);
      unsigned long long dl0 = *(const unsigned long long*)(dp + (size_t)b * 1024 + j00);
      unsigned long long dl1 = *(const unsigned long long*)(dp + (size_t)b * 1024 + j01);

      // poll: min over this group's 32 per-wave flags (one 128B line)
      for (;;) {
        u32x4 f0, f1, f2, f3, f4, f5, f6, f7;
        asm volatile(
          "global_load_dwordx4 %0, %8, off sc0 sc1\n\t"
          "global_load_dwordx4 %1, %8, off offset:16 sc0 sc1\n\t"
          "global_load_dwordx4 %2, %8, off offset:32 sc0 sc1\n\t"
          "global_load_dwordx4 %3, %8, off offset:48 sc0 sc1\n\t"
          "global_load_dwordx4 %4, %8, off offset:64 sc0 sc1\n\t"
          "global_load_dwordx4 %5, %8, off offset:80 sc0 sc1\n\t"
          "global_load_dwordx4 %6, %8, off offset:96 sc0 sc1\n\t"
          "global_load_dwordx4 %7, %8, off offset:112 sc0 sc1\n\t"
          "s_waitcnt vmcnt(0)"
          : "=&v"(f0), "=&v"(f1), "=&v"(f2), "=&v"(f3),
            "=&v"(f4), "=&v"(f5), "=&v"(f6), "=&v"(f7)
          : "v"(flg)
          : "memory");
        unsigned m = f0[0];
        #pragma unroll
        for (int q = 1; q < 4; ++q) m = f0[q] < m ? f0[q] : m;
        #pragma unroll
        for (int q = 0; q < 4; ++q) {
          m = f1[q] < m ? f1[q] : m;  m = f2[q] < m ? f2[q] : m;
          m = f3[q] < m ? f3[q] : m;  m = f4[q] < m ? f4[q] : m;
          m = f5[q] < m ? f5[q] : m;  m = f6[q] < m ? f6[q] : m;
          m = f7[q] < m ? f7[q] : m;
        }
        if (m >= target) break;
      }

      // poll's vmcnt(0) drained the previous group's publish stores ->
      // flush its pending flag now (r4's drain-then-flag invariant).
      if (pend_val && lane == 0)
        asm volatile("global_store_dword %0, %1, off sc0 sc1"
                     :: "v"(pend_ptr), "v"(pend_val) : "memory");

      // stage my 32B of the group's 8KB slab -> dense LDS tile [kt][bl][32]
      const unsigned short* gp = bufin + goff;
      f32x4 s0, s1;
      asm volatile(
        "global_load_dwordx4 %0, %2, off sc0 sc1\n\t"
        "global_load_dwordx4 %1, %2, off offset:16 sc0 sc1\n\t"
        "s_waitcnt vmcnt(0)"
        : "=&v"(s0), "=&v"(s1) : "v"(gp) : "memory");
      __builtin_amdgcn_sched_barrier(0);

      char* tile = (char*)&hs[g & 1][0];
      *(f32x4*)(tile + tid * 32)      = s0;
      *(f32x4*)(tile + tid * 32 + 16) = s1;
      __syncthreads();

      // y^T = R_chunk @ h^T  (B-frag: [kt][bl][lhi*8..+7], 2-way free reads)
      f32x4 acc[2][4] = {};
      const char* lr = tile + bl * 64 + lhi * 16;
      #pragma unroll
      for (int kt = 0; kt < 32; ++kt) {
        const bf16x8 a = *(const bf16x8*)(lr + kt * 256);
        acc[0][kt & 3] = mfma16(ra[0][kt], a, acc[0][kt & 3]);
        acc[1][kt & 3] = mfma16(ra[1][kt], a, acc[1][kt & 3]);
      }

      // blend; publish (no drain here -- next slot's vmcnt drains, then flag)
      f32x4 o0, o1;
      {
        const f32x4 y0 = (acc[0][0] + acc[0][1]) + (acc[0][2] + acc[0][3]) + wx0;
        const f32x4 y1 = (acc[1][0] + acc[1][1]) + (acc[1][2] + acc[1][3]) + wx1;
        #pragma unroll
        for (int r = 0; r < 4; ++r) {
          float c0 = fast_tanh(y0[r]);
          float d0 = bf2f((unsigned short)(dl0 >> (16 * r)));
          float h0v = hloc[g][0][r];
          float v0 = fmaf(d0, c0 - h0v, h0v);
          hloc[g][0][r] = v0; o0[r] = v0;
          float c1 = fast_tanh(y1[r]);
          float d1 = bf2f((unsigned short)(dl1 >> (16 * r)));
          float h1v = hloc[g][1][r];
          float v1 = fmaf(d1, c1 - h1v, h1v);
          hloc[g][1][r] = v1; o1[r] = v1;
        }
      }
      if (valid) {
        asm volatile("global_store_dwordx2 %0, %1, off sc0 sc1"
          :: "v"(bufout + (size_t)bl * 1024 + j00),
             "v"(pack4bf(o0[0], o0[1], o0[2], o0[3])) : "memory");
        asm volatile("global_store_dwordx2 %0, %1, off sc0 sc1"
          :: "v"(bufout + (size_t)bl * 1024 + j01),
             "v"(pack4bf(o1[0], o1[1], o1[2], o1[3])) : "memory");
        *(f32x4*)(outp + (size_t)b * 1024 + j00) = o0;
        *(f32x4*)(outp + (size_t)b * 1024 + j01) = o1;
      }
      pend_ptr = flg + slot;
      pend_val = (unsigned)t + 2u;
    }
  }
  // Final pending flag (value 1025) is never polled; dropping it is safe.
}

// ---------------------------------------------------------------------------
extern "C" void kernel_launch(void* const* d_in, const int* in_sizes, int n_in,
                              void* d_out, int out_size, void* d_ws, size_t ws_size,
                              hipStream_t stream) {
  const float* x    = (const float*)d_in[0];
  const float* h0   = (const float*)d_in[1];
  const float* Wx   = (const float*)d_in[2];
  const float* R    = (const float*)d_in[3];
  const float* bias = (const float*)d_in[4];
  const float* Wd   = (const float*)d_in[5];
  const float* bd   = (const float*)d_in[6];
  float* out = (float*)d_out;

  unsigned short* delta_ws = (unsigned short*)d_ws;
  char* ws = (char*)d_ws;

  // zero only the flag lines (sc0sc1-only traffic -> never dirty in any L2,
  // so the DMA memset cannot race a writeback).
  hipMemsetAsync(ws + FL_OFF, 0, 1024, stream);

  dim3 pg(256, 16);
  proj_kernel<<<pg, 256, 0, stream>>>(x, Wx, Wd, bias, bd, out, delta_ws);
  rnn_kernel<<<16, 256, 0, stream>>>(R, h0, out, delta_ws, ws);
}